// Round 1
// baseline (353.885 us; speedup 1.0000x reference)
//
#include <hip/hip_runtime.h>

// Problem constants (from reference)
#define BS 65536
#define NE 512
#define D  768
#define D4 192           // D / 4 (float4 granularity); 192 = 3 waves * 64 lanes
#define TOTAL4 (BS * D4) // 12,582,912 float4 elements

// Main kernel: gather codebook rows -> out, accumulate squared diff for loss.
// One thread per float4 (grid-stride). A wave (64 lanes) always lies within a
// single row since D4 % 64 == 0, so categories[row] is wave-uniform and the
// codebook read is 64 consecutive float4s (coalesced, L2-resident: 1.57 MB).
__global__ __launch_bounds__(256) void vq_main(
    const float4* __restrict__ inputs,
    const int*    __restrict__ categories,
    const float4* __restrict__ codebook,
    float4*       __restrict__ out,
    double*       __restrict__ loss_acc)
{
    int idx = blockIdx.x * 256 + threadIdx.x;
    const int stride = gridDim.x * 256;

    float acc = 0.0f;
    for (; idx < TOTAL4; idx += stride) {
        const int row = idx / D4;            // magic-mul, cheap
        const int col = idx - row * D4;
        const int cat = categories[row];     // wave-uniform broadcast load
        const float4 q = codebook[cat * D4 + col];
        const float4 x = inputs[idx];
        out[idx] = q;                        // quantized_st forward value == quantized
        const float dx = q.x - x.x;
        const float dy = q.y - x.y;
        const float dz = q.z - x.z;
        const float dw = q.w - x.w;
        acc += dx * dx + dy * dy + dz * dz + dw * dw;
    }

    // Wave (64-lane) shuffle reduction
    #pragma unroll
    for (int off = 32; off > 0; off >>= 1)
        acc += __shfl_down(acc, off, 64);

    __shared__ float wave_sums[4];
    const int lane = threadIdx.x & 63;
    const int wave = threadIdx.x >> 6;
    if (lane == 0) wave_sums[wave] = acc;
    __syncthreads();

    if (threadIdx.x == 0) {
        const float s = wave_sums[0] + wave_sums[1] + wave_sums[2] + wave_sums[3];
        atomicAdd(loss_acc, (double)s);      // device-scope, exact cross-block sum
    }
}

// Finalize: scale accumulated sum of squares -> loss scalar at out[BS*D].
// loss = (CODEBOOK_COST + COMMITMENT_COST) * mean(diff^2) = 1.25 * sum / (BS*D)
__global__ void vq_finalize(const double* __restrict__ loss_acc,
                            float* __restrict__ loss_out)
{
    *loss_out = (float)(*loss_acc * (1.25 / ((double)BS * (double)D)));
}

extern "C" void kernel_launch(void* const* d_in, const int* in_sizes, int n_in,
                              void* d_out, int out_size, void* d_ws, size_t ws_size,
                              hipStream_t stream) {
    const float4* inputs     = (const float4*)d_in[0];
    const int*    categories = (const int*)  d_in[1];  // jnp.int64 canonicalizes to int32
    const float4* codebook   = (const float4*)d_in[2];
    float*        out        = (float*)d_out;
    double*       loss_acc   = (double*)d_ws;

    // d_ws is poisoned 0xAA before every timed launch — zero the accumulator.
    hipMemsetAsync(d_ws, 0, sizeof(double), stream);

    // 4096 blocks x 256 threads -> 12 float4 per thread; saturates 256 CUs.
    vq_main<<<4096, 256, 0, stream>>>(inputs, categories, codebook,
                                      (float4*)out, loss_acc);
    vq_finalize<<<1, 1, 0, stream>>>(loss_acc, out + (size_t)BS * D);
}